// Round 14
// baseline (214.029 us; speedup 1.0000x reference)
//
#include <hip/hip_runtime.h>
#include <hip/hip_bf16.h>
#include <math.h>

#define NEG_SLOPE 0.2f
#define BCAP 6144     // bucket capacity (mean ~4100, 32-sigma safe)
#define ECHUNK 8192   // edges per k_bucket block

typedef __bf16 bf16x8 __attribute__((ext_vector_type(8)));
typedef float  f32x4  __attribute__((ext_vector_type(4)));

// manual bf16 <-> f32 bit conversions (RNE) — scalar fallback
__device__ __forceinline__ unsigned short f2b(float f) {
    union { float f; unsigned u; } c; c.f = f;
    unsigned r = (c.u + 0x7fffu + ((c.u >> 16) & 1u)) >> 16;
    return (unsigned short)r;
}
__device__ __forceinline__ float b2f(unsigned short s) {
    union { unsigned u; float f; } c; c.u = ((unsigned)s) << 16;
    return c.f;
}
// packed pair conversion: 2 f32 -> u32 of 2 bf16 (v_cvt_pk_bf16_f32)
__device__ __forceinline__ unsigned f2b2(float lo, float hi) {
    union { __hip_bfloat162 b; unsigned u; } c;
    c.b = __float22bfloat162_rn(make_float2(lo, hi));
    return c.u;
}

// ---------------- K1 (MFMA): xw1 = x @ W1 (bf16 out), al1_src/al1_dst; fused bcur zeroing ----------------
// 128 rows/block (2 x 64-row groups reusing the staged W1 tile)
__global__ __launch_bounds__(256) void k_feat1(
    const float* __restrict__ x, const float* __restrict__ W1,
    const float* __restrict__ a_src, const float* __restrict__ a_dst,
    unsigned short* __restrict__ xwb, float* __restrict__ als, float* __restrict__ ald,
    int* __restrict__ bcur, int NB, int N)
{
    int t = threadIdx.x;
    int gid = blockIdx.x * 256 + t;
    if (gid < NB) bcur[gid] = 0;          // fused bucket-cursor zeroing

    __shared__ unsigned short WT[64][136];   // W1^T bf16, padded row stride 272 B
    for (int pr = t; pr < 64 * 64; pr += 256) {   // 4096 k-pairs
        int k2 = pr >> 6, c = pr & 63;
        float w0 = W1[(2 * k2) * 64 + c];
        float w1 = W1[(2 * k2 + 1) * 64 + c];
        *(unsigned*)&WT[c][2 * k2] = f2b2(w0, w1);
    }
    __syncthreads();
    int wave = t >> 6, lane = t & 63;
    int lrow = lane & 15, lgrp = lane >> 4;

    bf16x8 bf[4][4];
#pragma unroll
    for (int ct = 0; ct < 4; ++ct)
#pragma unroll
        for (int ks = 0; ks < 4; ++ks)
            bf[ct][ks] = *(const bf16x8*)&WT[ct * 16 + lrow][ks * 32 + lgrp * 8];

    float asv[4], adv[4];
#pragma unroll
    for (int ct = 0; ct < 4; ++ct) { asv[ct] = a_src[ct * 16 + lrow]; adv[ct] = a_dst[ct * 16 + lrow]; }

    for (int rep = 0; rep < 2; ++rep) {
        int r0 = blockIdx.x * 128 + rep * 64 + wave * 16;
        if (r0 >= N) continue;    // wave-uniform

        f32x4 acc[4];
#pragma unroll
        for (int ct = 0; ct < 4; ++ct) acc[ct] = (f32x4){0.f, 0.f, 0.f, 0.f};

        int rowA = r0 + lrow; if (rowA >= N) rowA = N - 1;
        const float* xp = x + (size_t)rowA * 128 + lgrp * 8;
#pragma unroll
        for (int ks = 0; ks < 4; ++ks) {
            f32x4 v0 = *(const f32x4*)(xp + ks * 32);
            f32x4 v1 = *(const f32x4*)(xp + ks * 32 + 4);
            union { unsigned w[4]; bf16x8 b; } af;
            af.w[0] = f2b2(v0[0], v0[1]);
            af.w[1] = f2b2(v0[2], v0[3]);
            af.w[2] = f2b2(v1[0], v1[1]);
            af.w[3] = f2b2(v1[2], v1[3]);
#pragma unroll
            for (int ct = 0; ct < 4; ++ct)
                acc[ct] = __builtin_amdgcn_mfma_f32_16x16x32_bf16(af.b, bf[ct][ks], acc[ct], 0, 0, 0);
        }

#pragma unroll
        for (int q = 0; q < 4; ++q) {
            int row = r0 + lgrp * 4 + q;
            bool ok = row < N;
#pragma unroll
            for (int ct = 0; ct < 4; ++ct) {
                float v = acc[ct][q];
                if (ok) xwb[(size_t)row * 64 + ct * 16 + lrow] = f2b(v);
                float ps = v * asv[ct], pd = v * adv[ct];
#pragma unroll
                for (int m = 1; m < 16; m <<= 1) {
                    ps += __shfl_xor(ps, m, 64);
                    pd += __shfl_xor(pd, m, 64);
                }
                if (ok && lrow == 0) { als[row * 4 + ct] = ps; ald[row * 4 + ct] = pd; }
            }
        }
    }
}

// ---------------- K-feat (MFMA, K=64): xw = h @ W + logits; 128 rows/block ----------------
__global__ __launch_bounds__(256) void k_feat2(
    const unsigned short* __restrict__ hb, const float* __restrict__ W,
    const float* __restrict__ a_src, const float* __restrict__ a_dst,
    unsigned short* __restrict__ xwb, float* __restrict__ als, float* __restrict__ ald, int N)
{
    __shared__ unsigned short WT[64][72];   // 4B-aligned rows (144 B)
    int t = threadIdx.x;
    for (int pr = t; pr < 32 * 64; pr += 256) {   // 2048 k-pairs
        int k2 = pr >> 6, c = pr & 63;
        float w0 = W[(2 * k2) * 64 + c];
        float w1 = W[(2 * k2 + 1) * 64 + c];
        *(unsigned*)&WT[c][2 * k2] = f2b2(w0, w1);
    }
    __syncthreads();
    int wave = t >> 6, lane = t & 63;
    int lrow = lane & 15, lgrp = lane >> 4;

    bf16x8 bf[4][2];
#pragma unroll
    for (int ct = 0; ct < 4; ++ct)
#pragma unroll
        for (int ks = 0; ks < 2; ++ks)
            bf[ct][ks] = *(const bf16x8*)&WT[ct * 16 + lrow][ks * 32 + lgrp * 8];

    float asv[4], adv[4];
#pragma unroll
    for (int ct = 0; ct < 4; ++ct) { asv[ct] = a_src[ct * 16 + lrow]; adv[ct] = a_dst[ct * 16 + lrow]; }

    for (int rep = 0; rep < 2; ++rep) {
        int r0 = blockIdx.x * 128 + rep * 64 + wave * 16;
        if (r0 >= N) continue;

        f32x4 acc[4];
#pragma unroll
        for (int ct = 0; ct < 4; ++ct) acc[ct] = (f32x4){0.f, 0.f, 0.f, 0.f};

        int rowA = r0 + lrow; if (rowA >= N) rowA = N - 1;
        const unsigned short* hp = hb + (size_t)rowA * 64 + lgrp * 8;
#pragma unroll
        for (int ks = 0; ks < 2; ++ks) {
            bf16x8 af = *(const bf16x8*)(hp + ks * 32);
#pragma unroll
            for (int ct = 0; ct < 4; ++ct)
                acc[ct] = __builtin_amdgcn_mfma_f32_16x16x32_bf16(af, bf[ct][ks], acc[ct], 0, 0, 0);
        }

#pragma unroll
        for (int q = 0; q < 4; ++q) {
            int row = r0 + lgrp * 4 + q;
            bool ok = row < N;
#pragma unroll
            for (int ct = 0; ct < 4; ++ct) {
                float v = acc[ct][q];
                if (ok) xwb[(size_t)row * 64 + ct * 16 + lrow] = f2b(v);
                float ps = v * asv[ct], pd = v * adv[ct];
#pragma unroll
                for (int m = 1; m < 16; m <<= 1) {
                    ps += __shfl_xor(ps, m, 64);
                    pd += __shfl_xor(pd, m, 64);
                }
                if (ok && lrow == 0) { als[row * 4 + ct] = ps; ald[row * 4 + ct] = pd; }
            }
        }
    }
}

// ---------------- K-proj (MFMA, K=64): out = g @ Wp + bp (f32); 128 rows/block ----------------
__global__ __launch_bounds__(256) void k_proj(
    const unsigned short* __restrict__ gb, const float* __restrict__ Wp,
    const float* __restrict__ bp, float* __restrict__ out, int N)
{
    __shared__ unsigned short WT[64][72];
    int t = threadIdx.x;
    for (int pr = t; pr < 32 * 64; pr += 256) {
        int k2 = pr >> 6, c = pr & 63;
        float w0 = Wp[(2 * k2) * 64 + c];
        float w1 = Wp[(2 * k2 + 1) * 64 + c];
        *(unsigned*)&WT[c][2 * k2] = f2b2(w0, w1);
    }
    __syncthreads();
    int wave = t >> 6, lane = t & 63;
    int lrow = lane & 15, lgrp = lane >> 4;

    bf16x8 bf[4][2];
#pragma unroll
    for (int ct = 0; ct < 4; ++ct)
#pragma unroll
        for (int ks = 0; ks < 2; ++ks)
            bf[ct][ks] = *(const bf16x8*)&WT[ct * 16 + lrow][ks * 32 + lgrp * 8];

    float bpv[4];
#pragma unroll
    for (int ct = 0; ct < 4; ++ct) bpv[ct] = bp[ct * 16 + lrow];

    for (int rep = 0; rep < 2; ++rep) {
        int r0 = blockIdx.x * 128 + rep * 64 + wave * 16;
        if (r0 >= N) continue;

        f32x4 acc[4];
#pragma unroll
        for (int ct = 0; ct < 4; ++ct) acc[ct] = (f32x4){0.f, 0.f, 0.f, 0.f};

        int rowA = r0 + lrow; if (rowA >= N) rowA = N - 1;
        const unsigned short* gp = gb + (size_t)rowA * 64 + lgrp * 8;
#pragma unroll
        for (int ks = 0; ks < 2; ++ks) {
            bf16x8 af = *(const bf16x8*)(gp + ks * 32);
#pragma unroll
            for (int ct = 0; ct < 4; ++ct)
                acc[ct] = __builtin_amdgcn_mfma_f32_16x16x32_bf16(af, bf[ct][ks], acc[ct], 0, 0, 0);
        }

#pragma unroll
        for (int q = 0; q < 4; ++q) {
            int row = r0 + lgrp * 4 + q;
            if (row >= N) break;
#pragma unroll
            for (int ct = 0; ct < 4; ++ct)
                out[(size_t)row * 64 + ct * 16 + lrow] = acc[ct][q] + bpv[ct];
        }
    }
}

// ---------------- bucketed CSR build ----------------
// Pass A: two-level scatter; dst values staged in registers (single global read).
__global__ __launch_bounds__(256) void k_bucket(const int* __restrict__ src, const int* __restrict__ dst,
                                                int* __restrict__ bcur, unsigned* __restrict__ bbuf,
                                                int E, int NB) {
    __shared__ int cnt[512];
    __shared__ int base[512];
    int t = threadIdx.x;
    int e0 = blockIdx.x * ECHUNK;
    int e1 = e0 + ECHUNK; if (e1 > E) e1 = E;
    int dreg[ECHUNK / 256];
    for (int i = t; i < NB; i += 256) cnt[i] = 0;
    __syncthreads();
#pragma unroll
    for (int k = 0; k < ECHUNK / 256; ++k) {
        int i = e0 + k * 256 + t;
        int d = (i < e1) ? dst[i] : -1;
        dreg[k] = d;
        if (d >= 0) atomicAdd(&cnt[d >> 8], 1);
    }
    __syncthreads();
    for (int i = t; i < NB; i += 256) {
        int c = cnt[i];
        base[i] = c ? atomicAdd(&bcur[i], c) : 0;
        cnt[i] = 0;
    }
    __syncthreads();
#pragma unroll
    for (int k = 0; k < ECHUNK / 256; ++k) {
        int i = e0 + k * 256 + t;
        int d = dreg[k];
        if (d >= 0) {
            int b = d >> 8;
            int rel = atomicAdd(&cnt[b], 1);
            int pos = base[b] + rel;
            if (pos < BCAP)
                bbuf[(size_t)b * BCAP + pos] = ((unsigned)src[i] << 8) | (unsigned)(d & 255);
        }
    }
}

// one block per bucket: self-computed base -> stage edges in LDS -> histogram -> scan -> offs + placement
__global__ __launch_bounds__(256) void k_csr(const int* __restrict__ bcur, const unsigned* __restrict__ bbuf,
                                             int* __restrict__ offs, int* __restrict__ ssrc, int N) {
    __shared__ unsigned ebuf[BCAP];   // 24 KB
    __shared__ int cnt[256];
    __shared__ int scn[256];
    __shared__ int sbase;
    int t = threadIdx.x, b = blockIdx.x;
    int node = b * 256 + t;
    int nb = bcur[b]; if (nb > BCAP) nb = BCAP;
    const unsigned* bp = bbuf + (size_t)b * BCAP;

    // base = sum_{j<b} min(bcur[j],BCAP) + 256*b  (all buckets j<b are full)
    int ps = 0;
    for (int j = t; j < b; j += 256) {
        int c = bcur[j]; if (c > BCAP) c = BCAP;
        ps += c;
    }
    scn[t] = ps;
    cnt[t] = (node < N) ? 1 : 0;      // self-loop
    __syncthreads();
    for (int off = 128; off > 0; off >>= 1) {
        if (t < off) scn[t] += scn[t + off];
        __syncthreads();
    }
    if (t == 0) sbase = scn[0] + b * 256;
    __syncthreads();

    for (int j = t; j < nb; j += 256) {
        unsigned v = bp[j];
        ebuf[j] = v;
        atomicAdd(&cnt[v & 255u], 1);
    }
    __syncthreads();
    int d = cnt[t];
    scn[t] = d;
    __syncthreads();
    for (int off = 1; off < 256; off <<= 1) {
        int u = (t >= off) ? scn[t - off] : 0;
        __syncthreads();
        scn[t] += u;
        __syncthreads();
    }
    int o = sbase + scn[t] - d;       // exclusive global offset
    if (node < N) {
        offs[node] = o;
        ssrc[o] = node;               // self-loop first
        if (node == N - 1) offs[N] = o + d;
    }
    __syncthreads();
    cnt[t] = o + 1;                   // cursor past self-loop
    __syncthreads();
    for (int j = t; j < nb; j += 256) {
        unsigned v = ebuf[j];
        int dl = v & 255u;
        int pos = atomicAdd(&cnt[dl], 1);
        ssrc[pos] = (int)(v >> 8);
    }
}

// ---------------- K-agg: two-phase wave-cooperative segment softmax aggregate ----------------
__global__ __launch_bounds__(256) void k_aggregate(
    const int* __restrict__ offs, const int* __restrict__ ssrc,
    const unsigned short* __restrict__ xwb, const float* __restrict__ alsrc,
    const float* __restrict__ aldst, const float* __restrict__ bias,
    unsigned short* __restrict__ hout, int N)
{
    __shared__ float wls[4][32 * 8];   // 4 KB/wave
    int t = threadIdx.x;
    int wave = t >> 6, lane = t & 63;
    int n = blockIdx.x * 4 + wave;
    if (n >= N) return;
    int half = lane >> 5;          // which edge of the pair
    int cl = lane & 31;            // channel-pair index (channels 2cl, 2cl+1)
    int hp = cl >> 3;              // head (16 ch = 8 pairs per head)
    int s0 = offs[n], s1 = offs[n + 1];
    f32x4 adv = *(const f32x4*)(aldst + (size_t)n * 4);
    float* wl = wls[wave];
    int* wli = (int*)wl;
    const char* xb = (const char*)xwb;
    float ssum = 0.f, acc0 = 0.f, acc1 = 0.f;

    for (int c0 = s0; c0 < s1; c0 += 32) {
        int nb = s1 - c0; if (nb > 32) nb = 32;
        // ---- phase 1: lane = edge slot ----
        if (lane < nb) {
            int s = ssrc[c0 + lane];
            f32x4 al = *(const f32x4*)(alsrc + (size_t)s * 4);
            int o8 = lane * 8;
            int ob = s << 7;                           // s * 128 bytes
#pragma unroll
            for (int q = 0; q < 4; ++q) {
                float e = al[q] + adv[q];
                e = fmaxf(e, NEG_SLOPE * e);           // leaky_relu (slope<1)
                wl[o8 + 2 * q] = __expf(fminf(e, 60.f));
                wli[o8 + 2 * q + 1] = ob;
            }
        }
        // ---- phase 2: 2 edges per wave, 2 channels per lane; 8 gathers in flight ----
        int e = 0;
        for (; e + 16 <= nb; e += 16) {
#pragma unroll
            for (int u = 0; u < 8; ++u) {
                int idx = e + 2 * u + half;
                int bo = idx * 8 + hp * 2;
                float w = wl[bo];
                int   o = wli[bo + 1];
                unsigned pv = *(const unsigned*)(xb + o + cl * 4);
                union { unsigned u_; float f; } lo, hi;
                lo.u_ = pv << 16;
                hi.u_ = pv & 0xffff0000u;
                ssum += w;
                acc0 = fmaf(w, lo.f, acc0);
                acc1 = fmaf(w, hi.f, acc1);
            }
        }
        for (; e + 8 <= nb; e += 8) {
#pragma unroll
            for (int u = 0; u < 4; ++u) {
                int idx = e + 2 * u + half;
                int bo = idx * 8 + hp * 2;
                float w = wl[bo];
                int   o = wli[bo + 1];
                unsigned pv = *(const unsigned*)(xb + o + cl * 4);
                union { unsigned u_; float f; } lo, hi;
                lo.u_ = pv << 16;
                hi.u_ = pv & 0xffff0000u;
                ssum += w;
                acc0 = fmaf(w, lo.f, acc0);
                acc1 = fmaf(w, hi.f, acc1);
            }
        }
        for (; e < nb; e += 2) {
            int idx = e + half;
            if (idx < nb) {
                int bo = idx * 8 + hp * 2;
                float w = wl[bo];
                int   o = wli[bo + 1];
                unsigned pv = *(const unsigned*)(xb + o + cl * 4);
                union { unsigned u_; float f; } lo, hi;
                lo.u_ = pv << 16;
                hi.u_ = pv & 0xffff0000u;
                ssum += w;
                acc0 = fmaf(w, lo.f, acc0);
                acc1 = fmaf(w, hi.f, acc1);
            }
        }
    }

    // combine the two edge-halves
    ssum += __shfl_xor(ssum, 32, 64);
    acc0 += __shfl_xor(acc0, 32, 64);
    acc1 += __shfl_xor(acc1, 32, 64);
    float inv = 1.f / ssum;
    float2 bv = *(const float2*)(bias + 2 * cl);
    float h0 = fmaf(acc0, inv, bv.x);
    float h1 = fmaf(acc1, inv, bv.y);
    h0 = h0 > 0.f ? h0 : expm1f(h0);     // elu
    h1 = h1 > 0.f ? h1 : expm1f(h1);
    if (!half) {
        *(unsigned*)((char*)hout + ((size_t)n * 64 + cl * 2) * 2) = f2b2(h0, h1);
    }
}

// ---------------- launch ----------------
extern "C" void kernel_launch(void* const* d_in, const int* in_sizes, int n_in,
                              void* d_out, int out_size, void* d_ws, size_t ws_size,
                              hipStream_t stream) {
    const float* x   = (const float*)d_in[0];
    const int*   ei  = (const int*)d_in[1];
    const float* W1  = (const float*)d_in[2];
    const float* a1s = (const float*)d_in[3];
    const float* a1d = (const float*)d_in[4];
    const float* b1  = (const float*)d_in[5];
    const float* W2  = (const float*)d_in[6];
    const float* a2s = (const float*)d_in[7];
    const float* a2d = (const float*)d_in[8];
    const float* b2  = (const float*)d_in[9];
    const float* Wp  = (const float*)d_in[10];
    const float* bp  = (const float*)d_in[11];
    float* out = (float*)d_out;

    const int N = in_sizes[0] / 128;
    const int E = in_sizes[1] / 2;
    const int Etot = E + N;
    const int NB = (N + 255) >> 8;    // buckets of 256 dst nodes (<=512)
    const int* esrc = ei;
    const int* edst = ei + E;

    // workspace layout (~75 MB)
    char* p = (char*)d_ws;
    auto alloc = [&](size_t bytes) {
        char* r = p;
        p += (bytes + 255) & ~(size_t)255;
        return (void*)r;
    };
    unsigned short* xw1b = (unsigned short*)alloc((size_t)N * 64 * 2);
    unsigned short* xw2b = (unsigned short*)alloc((size_t)N * 64 * 2);
    unsigned short* h1b  = (unsigned short*)alloc((size_t)N * 64 * 2);
    unsigned short* h2b  = (unsigned short*)alloc((size_t)N * 64 * 2);
    float* al1sv = (float*)alloc((size_t)N * 4 * 4);
    float* al1dv = (float*)alloc((size_t)N * 4 * 4);
    float* al2sv = (float*)alloc((size_t)N * 4 * 4);
    float* al2dv = (float*)alloc((size_t)N * 4 * 4);
    int*   offs  = (int*)alloc((size_t)(N + 1) * 4);
    int*   ssrc  = (int*)alloc((size_t)Etot * 4);
    int*   bcur  = (int*)alloc((size_t)NB * 4);
    unsigned* bbuf = (unsigned*)alloc((size_t)NB * BCAP * 4);
    (void)ws_size; (void)n_in; (void)out_size;

    dim3 blk(256);
    int gEchunk = (E + ECHUNK - 1) / ECHUNK;
    int gN4    = (N + 3) / 4;
    int gN128  = (N + 127) / 128;

    k_feat1<<<gN128, blk, 0, stream>>>(x, W1, a1s, a1d, xw1b, al1sv, al1dv, bcur, NB, N);
    k_bucket<<<gEchunk, blk, 0, stream>>>(esrc, edst, bcur, bbuf, E, NB);
    k_csr<<<NB, blk, 0, stream>>>(bcur, bbuf, offs, ssrc, N);
    k_aggregate<<<gN4, blk, 0, stream>>>(offs, ssrc, xw1b, al1sv, al1dv, b1, h1b, N);
    k_feat2<<<gN128, blk, 0, stream>>>(h1b, W2, a2s, a2d, xw2b, al2sv, al2dv, N);
    k_aggregate<<<gN4, blk, 0, stream>>>(offs, ssrc, xw2b, al2sv, al2dv, b2, h2b, N);
    k_proj<<<gN128, blk, 0, stream>>>(h2b, Wp, bp, out, N);
}

// Round 15
// 198.532 us; speedup vs baseline: 1.0781x; 1.0781x over previous
//
#include <hip/hip_runtime.h>
#include <hip/hip_bf16.h>
#include <math.h>

#define NEG_SLOPE 0.2f
#define BCAP 6144     // bucket capacity (mean ~4100, 32-sigma safe)
#define ECHUNK 8192   // edges per k_bucket block

typedef __bf16 bf16x8 __attribute__((ext_vector_type(8)));
typedef float  f32x4  __attribute__((ext_vector_type(4)));

// manual bf16 <-> f32 bit conversions (RNE)
__device__ __forceinline__ unsigned short f2b(float f) {
    union { float f; unsigned u; } c; c.f = f;
    unsigned r = (c.u + 0x7fffu + ((c.u >> 16) & 1u)) >> 16;
    return (unsigned short)r;
}
__device__ __forceinline__ float b2f(unsigned short s) {
    union { unsigned u; float f; } c; c.u = ((unsigned)s) << 16;
    return c.f;
}

// ---------------- K1 (MFMA): xw1 = x @ W1 (bf16 out), al1_src/al1_dst; fused bcur zeroing ----------------
__global__ __launch_bounds__(256) void k_feat1(
    const float* __restrict__ x, const float* __restrict__ W1,
    const float* __restrict__ a_src, const float* __restrict__ a_dst,
    unsigned short* __restrict__ xwb, float* __restrict__ als, float* __restrict__ ald,
    int* __restrict__ bcur, int NB, int N)
{
    int t = threadIdx.x;
    int gid = blockIdx.x * 256 + t;
    if (gid < NB) bcur[gid] = 0;          // fused bucket-cursor zeroing

    __shared__ unsigned short WT[64][136];   // W1^T bf16, padded row stride 272 B
    for (int f = t; f < 128 * 64; f += 256) {
        int k = f >> 6, c = f & 63;
        WT[c][k] = f2b(W1[f]);
    }
    __syncthreads();
    int wave = t >> 6, lane = t & 63;
    int lrow = lane & 15, lgrp = lane >> 4;
    int r0 = blockIdx.x * 64 + wave * 16;
    if (r0 >= N) return;    // wave-uniform

    bf16x8 bf[4][4];
#pragma unroll
    for (int ct = 0; ct < 4; ++ct)
#pragma unroll
        for (int ks = 0; ks < 4; ++ks)
            bf[ct][ks] = *(const bf16x8*)&WT[ct * 16 + lrow][ks * 32 + lgrp * 8];

    f32x4 acc[4];
#pragma unroll
    for (int ct = 0; ct < 4; ++ct) acc[ct] = (f32x4){0.f, 0.f, 0.f, 0.f};

    int rowA = r0 + lrow; if (rowA >= N) rowA = N - 1;
    const float* xp = x + (size_t)rowA * 128 + lgrp * 8;
#pragma unroll
    for (int ks = 0; ks < 4; ++ks) {
        f32x4 v0 = *(const f32x4*)(xp + ks * 32);
        f32x4 v1 = *(const f32x4*)(xp + ks * 32 + 4);
        union { unsigned short s[8]; bf16x8 b; } af;
        af.s[0] = f2b(v0[0]); af.s[1] = f2b(v0[1]); af.s[2] = f2b(v0[2]); af.s[3] = f2b(v0[3]);
        af.s[4] = f2b(v1[0]); af.s[5] = f2b(v1[1]); af.s[6] = f2b(v1[2]); af.s[7] = f2b(v1[3]);
#pragma unroll
        for (int ct = 0; ct < 4; ++ct)
            acc[ct] = __builtin_amdgcn_mfma_f32_16x16x32_bf16(af.b, bf[ct][ks], acc[ct], 0, 0, 0);
    }

    float asv[4], adv[4];
#pragma unroll
    for (int ct = 0; ct < 4; ++ct) { asv[ct] = a_src[ct * 16 + lrow]; adv[ct] = a_dst[ct * 16 + lrow]; }
#pragma unroll
    for (int q = 0; q < 4; ++q) {
        int row = r0 + lgrp * 4 + q;
        bool ok = row < N;
#pragma unroll
        for (int ct = 0; ct < 4; ++ct) {
            float v = acc[ct][q];
            if (ok) xwb[(size_t)row * 64 + ct * 16 + lrow] = f2b(v);
            float ps = v * asv[ct], pd = v * adv[ct];
#pragma unroll
            for (int m = 1; m < 16; m <<= 1) {
                ps += __shfl_xor(ps, m, 64);
                pd += __shfl_xor(pd, m, 64);
            }
            if (ok && lrow == 0) { als[row * 4 + ct] = ps; ald[row * 4 + ct] = pd; }
        }
    }
}

// ---------------- K-feat (MFMA, K=64): xw = h @ W + logits ----------------
__global__ __launch_bounds__(256) void k_feat2(
    const unsigned short* __restrict__ hb, const float* __restrict__ W,
    const float* __restrict__ a_src, const float* __restrict__ a_dst,
    unsigned short* __restrict__ xwb, float* __restrict__ als, float* __restrict__ ald, int N)
{
    __shared__ unsigned short WT[64][72];
    int t = threadIdx.x;
    for (int f = t; f < 64 * 64; f += 256) {
        int k = f >> 6, c = f & 63;
        WT[c][k] = f2b(W[f]);
    }
    __syncthreads();
    int wave = t >> 6, lane = t & 63;
    int lrow = lane & 15, lgrp = lane >> 4;
    int r0 = blockIdx.x * 64 + wave * 16;
    if (r0 >= N) return;

    bf16x8 bf[4][2];
#pragma unroll
    for (int ct = 0; ct < 4; ++ct)
#pragma unroll
        for (int ks = 0; ks < 2; ++ks)
            bf[ct][ks] = *(const bf16x8*)&WT[ct * 16 + lrow][ks * 32 + lgrp * 8];

    f32x4 acc[4];
#pragma unroll
    for (int ct = 0; ct < 4; ++ct) acc[ct] = (f32x4){0.f, 0.f, 0.f, 0.f};

    int rowA = r0 + lrow; if (rowA >= N) rowA = N - 1;
    const unsigned short* hp = hb + (size_t)rowA * 64 + lgrp * 8;
#pragma unroll
    for (int ks = 0; ks < 2; ++ks) {
        bf16x8 af = *(const bf16x8*)(hp + ks * 32);
#pragma unroll
        for (int ct = 0; ct < 4; ++ct)
            acc[ct] = __builtin_amdgcn_mfma_f32_16x16x32_bf16(af, bf[ct][ks], acc[ct], 0, 0, 0);
    }

    float asv[4], adv[4];
#pragma unroll
    for (int ct = 0; ct < 4; ++ct) { asv[ct] = a_src[ct * 16 + lrow]; adv[ct] = a_dst[ct * 16 + lrow]; }
#pragma unroll
    for (int q = 0; q < 4; ++q) {
        int row = r0 + lgrp * 4 + q;
        bool ok = row < N;
#pragma unroll
        for (int ct = 0; ct < 4; ++ct) {
            float v = acc[ct][q];
            if (ok) xwb[(size_t)row * 64 + ct * 16 + lrow] = f2b(v);
            float ps = v * asv[ct], pd = v * adv[ct];
#pragma unroll
            for (int m = 1; m < 16; m <<= 1) {
                ps += __shfl_xor(ps, m, 64);
                pd += __shfl_xor(pd, m, 64);
            }
            if (ok && lrow == 0) { als[row * 4 + ct] = ps; ald[row * 4 + ct] = pd; }
        }
    }
}

// ---------------- K-proj (MFMA, K=64): out = g @ Wp + bp (f32) ----------------
__global__ __launch_bounds__(256) void k_proj(
    const unsigned short* __restrict__ gb, const float* __restrict__ Wp,
    const float* __restrict__ bp, float* __restrict__ out, int N)
{
    __shared__ unsigned short WT[64][72];
    int t = threadIdx.x;
    for (int f = t; f < 64 * 64; f += 256) {
        int k = f >> 6, c = f & 63;
        WT[c][k] = f2b(Wp[f]);
    }
    __syncthreads();
    int wave = t >> 6, lane = t & 63;
    int lrow = lane & 15, lgrp = lane >> 4;
    int r0 = blockIdx.x * 64 + wave * 16;
    if (r0 >= N) return;

    bf16x8 bf[4][2];
#pragma unroll
    for (int ct = 0; ct < 4; ++ct)
#pragma unroll
        for (int ks = 0; ks < 2; ++ks)
            bf[ct][ks] = *(const bf16x8*)&WT[ct * 16 + lrow][ks * 32 + lgrp * 8];

    f32x4 acc[4];
#pragma unroll
    for (int ct = 0; ct < 4; ++ct) acc[ct] = (f32x4){0.f, 0.f, 0.f, 0.f};

    int rowA = r0 + lrow; if (rowA >= N) rowA = N - 1;
    const unsigned short* gp = gb + (size_t)rowA * 64 + lgrp * 8;
#pragma unroll
    for (int ks = 0; ks < 2; ++ks) {
        bf16x8 af = *(const bf16x8*)(gp + ks * 32);
#pragma unroll
        for (int ct = 0; ct < 4; ++ct)
            acc[ct] = __builtin_amdgcn_mfma_f32_16x16x32_bf16(af, bf[ct][ks], acc[ct], 0, 0, 0);
    }

    float bpv[4];
#pragma unroll
    for (int ct = 0; ct < 4; ++ct) bpv[ct] = bp[ct * 16 + lrow];
#pragma unroll
    for (int q = 0; q < 4; ++q) {
        int row = r0 + lgrp * 4 + q;
        if (row >= N) break;
#pragma unroll
        for (int ct = 0; ct < 4; ++ct)
            out[(size_t)row * 64 + ct * 16 + lrow] = acc[ct][q] + bpv[ct];
    }
}

// ---------------- bucketed CSR build ----------------
// Pass A: two-level scatter; dst values staged in registers (single global read).
__global__ __launch_bounds__(256) void k_bucket(const int* __restrict__ src, const int* __restrict__ dst,
                                                int* __restrict__ bcur, unsigned* __restrict__ bbuf,
                                                int E, int NB) {
    __shared__ int cnt[512];
    __shared__ int base[512];
    int t = threadIdx.x;
    int e0 = blockIdx.x * ECHUNK;
    int e1 = e0 + ECHUNK; if (e1 > E) e1 = E;
    int dreg[ECHUNK / 256];
    for (int i = t; i < NB; i += 256) cnt[i] = 0;
    __syncthreads();
#pragma unroll
    for (int k = 0; k < ECHUNK / 256; ++k) {
        int i = e0 + k * 256 + t;
        int d = (i < e1) ? dst[i] : -1;
        dreg[k] = d;
        if (d >= 0) atomicAdd(&cnt[d >> 8], 1);
    }
    __syncthreads();
    for (int i = t; i < NB; i += 256) {
        int c = cnt[i];
        base[i] = c ? atomicAdd(&bcur[i], c) : 0;
        cnt[i] = 0;
    }
    __syncthreads();
#pragma unroll
    for (int k = 0; k < ECHUNK / 256; ++k) {
        int i = e0 + k * 256 + t;
        int d = dreg[k];
        if (d >= 0) {
            int b = d >> 8;
            int rel = atomicAdd(&cnt[b], 1);
            int pos = base[b] + rel;
            if (pos < BCAP)
                bbuf[(size_t)b * BCAP + pos] = ((unsigned)src[i] << 8) | (unsigned)(d & 255);
        }
    }
}

// one block per bucket: self-computed base -> stage edges in LDS -> histogram -> scan -> offs + placement
__global__ __launch_bounds__(256) void k_csr(const int* __restrict__ bcur, const unsigned* __restrict__ bbuf,
                                             int* __restrict__ offs, int* __restrict__ ssrc, int N) {
    __shared__ unsigned ebuf[BCAP];   // 24 KB
    __shared__ int cnt[256];
    __shared__ int scn[256];
    __shared__ int sbase;
    int t = threadIdx.x, b = blockIdx.x;
    int node = b * 256 + t;
    int nb = bcur[b]; if (nb > BCAP) nb = BCAP;
    const unsigned* bp = bbuf + (size_t)b * BCAP;

    // base = sum_{j<b} min(bcur[j],BCAP) + 256*b  (all buckets j<b are full)
    int ps = 0;
    for (int j = t; j < b; j += 256) {
        int c = bcur[j]; if (c > BCAP) c = BCAP;
        ps += c;
    }
    scn[t] = ps;
    cnt[t] = (node < N) ? 1 : 0;      // self-loop
    __syncthreads();
    for (int off = 128; off > 0; off >>= 1) {
        if (t < off) scn[t] += scn[t + off];
        __syncthreads();
    }
    if (t == 0) sbase = scn[0] + b * 256;
    __syncthreads();

    for (int j = t; j < nb; j += 256) {
        unsigned v = bp[j];
        ebuf[j] = v;
        atomicAdd(&cnt[v & 255u], 1);
    }
    __syncthreads();
    int d = cnt[t];
    scn[t] = d;
    __syncthreads();
    for (int off = 1; off < 256; off <<= 1) {
        int u = (t >= off) ? scn[t - off] : 0;
        __syncthreads();
        scn[t] += u;
        __syncthreads();
    }
    int o = sbase + scn[t] - d;       // exclusive global offset
    if (node < N) {
        offs[node] = o;
        ssrc[o] = node;               // self-loop first
        if (node == N - 1) offs[N] = o + d;
    }
    __syncthreads();
    cnt[t] = o + 1;                   // cursor past self-loop
    __syncthreads();
    for (int j = t; j < nb; j += 256) {
        unsigned v = ebuf[j];
        int dl = v & 255u;
        int pos = atomicAdd(&cnt[dl], 1);
        ssrc[pos] = (int)(v >> 8);
    }
}

// ---------------- K-agg: two-phase wave-cooperative segment softmax aggregate ----------------
__global__ __launch_bounds__(256) void k_aggregate(
    const int* __restrict__ offs, const int* __restrict__ ssrc,
    const unsigned short* __restrict__ xwb, const float* __restrict__ alsrc,
    const float* __restrict__ aldst, const float* __restrict__ bias,
    unsigned short* __restrict__ hout, int N)
{
    __shared__ float wls[4][32 * 8];   // 4 KB/wave
    int t = threadIdx.x;
    int wave = t >> 6, lane = t & 63;
    int n = blockIdx.x * 4 + wave;
    if (n >= N) return;
    int half = lane >> 5;          // which edge of the pair
    int cl = lane & 31;            // channel-pair index (channels 2cl, 2cl+1)
    int hp = cl >> 3;              // head (16 ch = 8 pairs per head)
    int s0 = offs[n], s1 = offs[n + 1];
    f32x4 adv = *(const f32x4*)(aldst + (size_t)n * 4);
    float* wl = wls[wave];
    int* wli = (int*)wl;
    const char* xb = (const char*)xwb;
    float ssum = 0.f, acc0 = 0.f, acc1 = 0.f;

    for (int c0 = s0; c0 < s1; c0 += 32) {
        int nb = s1 - c0; if (nb > 32) nb = 32;
        // ---- phase 1: lane = edge slot ----
        if (lane < nb) {
            int s = ssrc[c0 + lane];
            f32x4 al = *(const f32x4*)(alsrc + (size_t)s * 4);
            int o8 = lane * 8;
            int ob = s << 7;                           // s * 128 bytes
#pragma unroll
            for (int q = 0; q < 4; ++q) {
                float e = al[q] + adv[q];
                e = fmaxf(e, NEG_SLOPE * e);           // leaky_relu (slope<1)
                wl[o8 + 2 * q] = __expf(fminf(e, 60.f));
                wli[o8 + 2 * q + 1] = ob;
            }
        }
        // ---- phase 2: 2 edges per wave, 2 channels per lane; 8 gathers in flight ----
        int e = 0;
        for (; e + 16 <= nb; e += 16) {
#pragma unroll
            for (int u = 0; u < 8; ++u) {
                int idx = e + 2 * u + half;
                int bo = idx * 8 + hp * 2;
                float w = wl[bo];
                int   o = wli[bo + 1];
                unsigned pv = *(const unsigned*)(xb + o + cl * 4);
                union { unsigned u_; float f; } lo, hi;
                lo.u_ = pv << 16;
                hi.u_ = pv & 0xffff0000u;
                ssum += w;
                acc0 = fmaf(w, lo.f, acc0);
                acc1 = fmaf(w, hi.f, acc1);
            }
        }
        for (; e + 8 <= nb; e += 8) {
#pragma unroll
            for (int u = 0; u < 4; ++u) {
                int idx = e + 2 * u + half;
                int bo = idx * 8 + hp * 2;
                float w = wl[bo];
                int   o = wli[bo + 1];
                unsigned pv = *(const unsigned*)(xb + o + cl * 4);
                union { unsigned u_; float f; } lo, hi;
                lo.u_ = pv << 16;
                hi.u_ = pv & 0xffff0000u;
                ssum += w;
                acc0 = fmaf(w, lo.f, acc0);
                acc1 = fmaf(w, hi.f, acc1);
            }
        }
        for (; e < nb; e += 2) {
            int idx = e + half;
            if (idx < nb) {
                int bo = idx * 8 + hp * 2;
                float w = wl[bo];
                int   o = wli[bo + 1];
                unsigned pv = *(const unsigned*)(xb + o + cl * 4);
                union { unsigned u_; float f; } lo, hi;
                lo.u_ = pv << 16;
                hi.u_ = pv & 0xffff0000u;
                ssum += w;
                acc0 = fmaf(w, lo.f, acc0);
                acc1 = fmaf(w, hi.f, acc1);
            }
        }
    }

    // combine the two edge-halves
    ssum += __shfl_xor(ssum, 32, 64);
    acc0 += __shfl_xor(acc0, 32, 64);
    acc1 += __shfl_xor(acc1, 32, 64);
    float inv = 1.f / ssum;
    float2 bv = *(const float2*)(bias + 2 * cl);
    float h0 = fmaf(acc0, inv, bv.x);
    float h1 = fmaf(acc1, inv, bv.y);
    h0 = h0 > 0.f ? h0 : expm1f(h0);     // elu
    h1 = h1 > 0.f ? h1 : expm1f(h1);
    if (!half) {
        union { unsigned short s2[2]; unsigned u; } st;
        st.s2[0] = f2b(h0); st.s2[1] = f2b(h1);
        *(unsigned*)((char*)hout + ((size_t)n * 64 + cl * 2) * 2) = st.u;
    }
}

// ---------------- launch ----------------
extern "C" void kernel_launch(void* const* d_in, const int* in_sizes, int n_in,
                              void* d_out, int out_size, void* d_ws, size_t ws_size,
                              hipStream_t stream) {
    const float* x   = (const float*)d_in[0];
    const int*   ei  = (const int*)d_in[1];
    const float* W1  = (const float*)d_in[2];
    const float* a1s = (const float*)d_in[3];
    const float* a1d = (const float*)d_in[4];
    const float* b1  = (const float*)d_in[5];
    const float* W2  = (const float*)d_in[6];
    const float* a2s = (const float*)d_in[7];
    const float* a2d = (const float*)d_in[8];
    const float* b2  = (const float*)d_in[9];
    const float* Wp  = (const float*)d_in[10];
    const float* bp  = (const float*)d_in[11];
    float* out = (float*)d_out;

    const int N = in_sizes[0] / 128;
    const int E = in_sizes[1] / 2;
    const int Etot = E + N;
    const int NB = (N + 255) >> 8;    // buckets of 256 dst nodes (<=512)
    const int* esrc = ei;
    const int* edst = ei + E;

    // workspace layout (~75 MB)
    char* p = (char*)d_ws;
    auto alloc = [&](size_t bytes) {
        char* r = p;
        p += (bytes + 255) & ~(size_t)255;
        return (void*)r;
    };
    unsigned short* xw1b = (unsigned short*)alloc((size_t)N * 64 * 2);
    unsigned short* xw2b = (unsigned short*)alloc((size_t)N * 64 * 2);
    unsigned short* h1b  = (unsigned short*)alloc((size_t)N * 64 * 2);
    unsigned short* h2b  = (unsigned short*)alloc((size_t)N * 64 * 2);
    float* al1sv = (float*)alloc((size_t)N * 4 * 4);
    float* al1dv = (float*)alloc((size_t)N * 4 * 4);
    float* al2sv = (float*)alloc((size_t)N * 4 * 4);
    float* al2dv = (float*)alloc((size_t)N * 4 * 4);
    int*   offs  = (int*)alloc((size_t)(N + 1) * 4);
    int*   ssrc  = (int*)alloc((size_t)Etot * 4);
    int*   bcur  = (int*)alloc((size_t)NB * 4);
    unsigned* bbuf = (unsigned*)alloc((size_t)NB * BCAP * 4);
    (void)ws_size; (void)n_in; (void)out_size;

    dim3 blk(256);
    int gEchunk = (E + ECHUNK - 1) / ECHUNK;
    int gN4   = (N + 3) / 4;
    int gN64  = (N + 63) / 64;

    k_feat1<<<gN64, blk, 0, stream>>>(x, W1, a1s, a1d, xw1b, al1sv, al1dv, bcur, NB, N);
    k_bucket<<<gEchunk, blk, 0, stream>>>(esrc, edst, bcur, bbuf, E, NB);
    k_csr<<<NB, blk, 0, stream>>>(bcur, bbuf, offs, ssrc, N);
    k_aggregate<<<gN4, blk, 0, stream>>>(offs, ssrc, xw1b, al1sv, al1dv, b1, h1b, N);
    k_feat2<<<gN64, blk, 0, stream>>>(h1b, W2, a2s, a2d, xw2b, al2sv, al2dv, N);
    k_aggregate<<<gN4, blk, 0, stream>>>(offs, ssrc, xw2b, al2sv, al2dv, b2, h2b, N);
    k_proj<<<gN64, blk, 0, stream>>>(h2b, Wp, bp, out, N);
}

// Round 16
// 195.725 us; speedup vs baseline: 1.0935x; 1.0143x over previous
//
#include <hip/hip_runtime.h>
#include <hip/hip_bf16.h>
#include <math.h>

#define NEG_SLOPE 0.2f
#define BCAP 6144     // bucket capacity (mean ~4100, 32-sigma safe)
#define ECHUNK 4096   // edges per k_bucket block (391 blocks -> ~1.5 waves/SIMD)

typedef __bf16 bf16x8 __attribute__((ext_vector_type(8)));
typedef float  f32x4  __attribute__((ext_vector_type(4)));

// manual bf16 <-> f32 bit conversions (RNE)
__device__ __forceinline__ unsigned short f2b(float f) {
    union { float f; unsigned u; } c; c.f = f;
    unsigned r = (c.u + 0x7fffu + ((c.u >> 16) & 1u)) >> 16;
    return (unsigned short)r;
}
__device__ __forceinline__ float b2f(unsigned short s) {
    union { unsigned u; float f; } c; c.u = ((unsigned)s) << 16;
    return c.f;
}

// ---------------- K1 (MFMA): xw1 = x @ W1 (bf16 out), al1_src/al1_dst; fused bcur zeroing ----------------
__global__ __launch_bounds__(256) void k_feat1(
    const float* __restrict__ x, const float* __restrict__ W1,
    const float* __restrict__ a_src, const float* __restrict__ a_dst,
    unsigned short* __restrict__ xwb, float* __restrict__ als, float* __restrict__ ald,
    int* __restrict__ bcur, int NB, int N)
{
    int t = threadIdx.x;
    int gid = blockIdx.x * 256 + t;
    if (gid < NB) bcur[gid] = 0;          // fused bucket-cursor zeroing

    __shared__ unsigned short WT[64][136];   // W1^T bf16, padded row stride 272 B
    for (int f = t; f < 128 * 64; f += 256) {
        int k = f >> 6, c = f & 63;
        WT[c][k] = f2b(W1[f]);
    }
    __syncthreads();
    int wave = t >> 6, lane = t & 63;
    int lrow = lane & 15, lgrp = lane >> 4;
    int r0 = blockIdx.x * 64 + wave * 16;
    if (r0 >= N) return;    // wave-uniform

    bf16x8 bf[4][4];
#pragma unroll
    for (int ct = 0; ct < 4; ++ct)
#pragma unroll
        for (int ks = 0; ks < 4; ++ks)
            bf[ct][ks] = *(const bf16x8*)&WT[ct * 16 + lrow][ks * 32 + lgrp * 8];

    f32x4 acc[4];
#pragma unroll
    for (int ct = 0; ct < 4; ++ct) acc[ct] = (f32x4){0.f, 0.f, 0.f, 0.f};

    int rowA = r0 + lrow; if (rowA >= N) rowA = N - 1;
    const float* xp = x + (size_t)rowA * 128 + lgrp * 8;
#pragma unroll
    for (int ks = 0; ks < 4; ++ks) {
        f32x4 v0 = *(const f32x4*)(xp + ks * 32);
        f32x4 v1 = *(const f32x4*)(xp + ks * 32 + 4);
        union { unsigned short s[8]; bf16x8 b; } af;
        af.s[0] = f2b(v0[0]); af.s[1] = f2b(v0[1]); af.s[2] = f2b(v0[2]); af.s[3] = f2b(v0[3]);
        af.s[4] = f2b(v1[0]); af.s[5] = f2b(v1[1]); af.s[6] = f2b(v1[2]); af.s[7] = f2b(v1[3]);
#pragma unroll
        for (int ct = 0; ct < 4; ++ct)
            acc[ct] = __builtin_amdgcn_mfma_f32_16x16x32_bf16(af.b, bf[ct][ks], acc[ct], 0, 0, 0);
    }

    float asv[4], adv[4];
#pragma unroll
    for (int ct = 0; ct < 4; ++ct) { asv[ct] = a_src[ct * 16 + lrow]; adv[ct] = a_dst[ct * 16 + lrow]; }
#pragma unroll
    for (int q = 0; q < 4; ++q) {
        int row = r0 + lgrp * 4 + q;
        bool ok = row < N;
#pragma unroll
        for (int ct = 0; ct < 4; ++ct) {
            float v = acc[ct][q];
            if (ok) xwb[(size_t)row * 64 + ct * 16 + lrow] = f2b(v);
            float ps = v * asv[ct], pd = v * adv[ct];
#pragma unroll
            for (int m = 1; m < 16; m <<= 1) {
                ps += __shfl_xor(ps, m, 64);
                pd += __shfl_xor(pd, m, 64);
            }
            if (ok && lrow == 0) { als[row * 4 + ct] = ps; ald[row * 4 + ct] = pd; }
        }
    }
}

// ---------------- K-feat (MFMA, K=64): xw = h @ W + logits ----------------
__global__ __launch_bounds__(256) void k_feat2(
    const unsigned short* __restrict__ hb, const float* __restrict__ W,
    const float* __restrict__ a_src, const float* __restrict__ a_dst,
    unsigned short* __restrict__ xwb, float* __restrict__ als, float* __restrict__ ald, int N)
{
    __shared__ unsigned short WT[64][72];
    int t = threadIdx.x;
    for (int f = t; f < 64 * 64; f += 256) {
        int k = f >> 6, c = f & 63;
        WT[c][k] = f2b(W[f]);
    }
    __syncthreads();
    int wave = t >> 6, lane = t & 63;
    int lrow = lane & 15, lgrp = lane >> 4;
    int r0 = blockIdx.x * 64 + wave * 16;
    if (r0 >= N) return;

    bf16x8 bf[4][2];
#pragma unroll
    for (int ct = 0; ct < 4; ++ct)
#pragma unroll
        for (int ks = 0; ks < 2; ++ks)
            bf[ct][ks] = *(const bf16x8*)&WT[ct * 16 + lrow][ks * 32 + lgrp * 8];

    f32x4 acc[4];
#pragma unroll
    for (int ct = 0; ct < 4; ++ct) acc[ct] = (f32x4){0.f, 0.f, 0.f, 0.f};

    int rowA = r0 + lrow; if (rowA >= N) rowA = N - 1;
    const unsigned short* hp = hb + (size_t)rowA * 64 + lgrp * 8;
#pragma unroll
    for (int ks = 0; ks < 2; ++ks) {
        bf16x8 af = *(const bf16x8*)(hp + ks * 32);
#pragma unroll
        for (int ct = 0; ct < 4; ++ct)
            acc[ct] = __builtin_amdgcn_mfma_f32_16x16x32_bf16(af, bf[ct][ks], acc[ct], 0, 0, 0);
    }

    float asv[4], adv[4];
#pragma unroll
    for (int ct = 0; ct < 4; ++ct) { asv[ct] = a_src[ct * 16 + lrow]; adv[ct] = a_dst[ct * 16 + lrow]; }
#pragma unroll
    for (int q = 0; q < 4; ++q) {
        int row = r0 + lgrp * 4 + q;
        bool ok = row < N;
#pragma unroll
        for (int ct = 0; ct < 4; ++ct) {
            float v = acc[ct][q];
            if (ok) xwb[(size_t)row * 64 + ct * 16 + lrow] = f2b(v);
            float ps = v * asv[ct], pd = v * adv[ct];
#pragma unroll
            for (int m = 1; m < 16; m <<= 1) {
                ps += __shfl_xor(ps, m, 64);
                pd += __shfl_xor(pd, m, 64);
            }
            if (ok && lrow == 0) { als[row * 4 + ct] = ps; ald[row * 4 + ct] = pd; }
        }
    }
}

// ---------------- K-proj (MFMA, K=64): out = g @ Wp + bp (f32) ----------------
__global__ __launch_bounds__(256) void k_proj(
    const unsigned short* __restrict__ gb, const float* __restrict__ Wp,
    const float* __restrict__ bp, float* __restrict__ out, int N)
{
    __shared__ unsigned short WT[64][72];
    int t = threadIdx.x;
    for (int f = t; f < 64 * 64; f += 256) {
        int k = f >> 6, c = f & 63;
        WT[c][k] = f2b(Wp[f]);
    }
    __syncthreads();
    int wave = t >> 6, lane = t & 63;
    int lrow = lane & 15, lgrp = lane >> 4;
    int r0 = blockIdx.x * 64 + wave * 16;
    if (r0 >= N) return;

    bf16x8 bf[4][2];
#pragma unroll
    for (int ct = 0; ct < 4; ++ct)
#pragma unroll
        for (int ks = 0; ks < 2; ++ks)
            bf[ct][ks] = *(const bf16x8*)&WT[ct * 16 + lrow][ks * 32 + lgrp * 8];

    f32x4 acc[4];
#pragma unroll
    for (int ct = 0; ct < 4; ++ct) acc[ct] = (f32x4){0.f, 0.f, 0.f, 0.f};

    int rowA = r0 + lrow; if (rowA >= N) rowA = N - 1;
    const unsigned short* gp = gb + (size_t)rowA * 64 + lgrp * 8;
#pragma unroll
    for (int ks = 0; ks < 2; ++ks) {
        bf16x8 af = *(const bf16x8*)(gp + ks * 32);
#pragma unroll
        for (int ct = 0; ct < 4; ++ct)
            acc[ct] = __builtin_amdgcn_mfma_f32_16x16x32_bf16(af, bf[ct][ks], acc[ct], 0, 0, 0);
    }

    float bpv[4];
#pragma unroll
    for (int ct = 0; ct < 4; ++ct) bpv[ct] = bp[ct * 16 + lrow];
#pragma unroll
    for (int q = 0; q < 4; ++q) {
        int row = r0 + lgrp * 4 + q;
        if (row >= N) break;
#pragma unroll
        for (int ct = 0; ct < 4; ++ct)
            out[(size_t)row * 64 + ct * 16 + lrow] = acc[ct][q] + bpv[ct];
    }
}

// ---------------- bucketed CSR build ----------------
// Pass A: two-level scatter; dst values staged in registers (single global read).
__global__ __launch_bounds__(256) void k_bucket(const int* __restrict__ src, const int* __restrict__ dst,
                                                int* __restrict__ bcur, unsigned* __restrict__ bbuf,
                                                int E, int NB) {
    __shared__ int cnt[512];
    __shared__ int base[512];
    int t = threadIdx.x;
    int e0 = blockIdx.x * ECHUNK;
    int e1 = e0 + ECHUNK; if (e1 > E) e1 = E;
    int dreg[ECHUNK / 256];
    for (int i = t; i < NB; i += 256) cnt[i] = 0;
    __syncthreads();
#pragma unroll
    for (int k = 0; k < ECHUNK / 256; ++k) {
        int i = e0 + k * 256 + t;
        int d = (i < e1) ? dst[i] : -1;
        dreg[k] = d;
        if (d >= 0) atomicAdd(&cnt[d >> 8], 1);
    }
    __syncthreads();
    for (int i = t; i < NB; i += 256) {
        int c = cnt[i];
        base[i] = c ? atomicAdd(&bcur[i], c) : 0;
        cnt[i] = 0;
    }
    __syncthreads();
#pragma unroll
    for (int k = 0; k < ECHUNK / 256; ++k) {
        int i = e0 + k * 256 + t;
        int d = dreg[k];
        if (d >= 0) {
            int b = d >> 8;
            int rel = atomicAdd(&cnt[b], 1);
            int pos = base[b] + rel;
            if (pos < BCAP)
                bbuf[(size_t)b * BCAP + pos] = ((unsigned)src[i] << 8) | (unsigned)(d & 255);
        }
    }
}

// one block per bucket: self-computed base -> stage edges in LDS -> histogram -> scan -> offs + placement
__global__ __launch_bounds__(256) void k_csr(const int* __restrict__ bcur, const unsigned* __restrict__ bbuf,
                                             int* __restrict__ offs, int* __restrict__ ssrc, int N) {
    __shared__ unsigned ebuf[BCAP];   // 24 KB
    __shared__ int cnt[256];
    __shared__ int scn[256];
    __shared__ int sbase;
    int t = threadIdx.x, b = blockIdx.x;
    int node = b * 256 + t;
    int nb = bcur[b]; if (nb > BCAP) nb = BCAP;
    const unsigned* bp = bbuf + (size_t)b * BCAP;

    // base = sum_{j<b} min(bcur[j],BCAP) + 256*b  (all buckets j<b are full)
    int ps = 0;
    for (int j = t; j < b; j += 256) {
        int c = bcur[j]; if (c > BCAP) c = BCAP;
        ps += c;
    }
    scn[t] = ps;
    cnt[t] = (node < N) ? 1 : 0;      // self-loop
    __syncthreads();
    for (int off = 128; off > 0; off >>= 1) {
        if (t < off) scn[t] += scn[t + off];
        __syncthreads();
    }
    if (t == 0) sbase = scn[0] + b * 256;
    __syncthreads();

    for (int j = t; j < nb; j += 256) {
        unsigned v = bp[j];
        ebuf[j] = v;
        atomicAdd(&cnt[v & 255u], 1);
    }
    __syncthreads();
    int d = cnt[t];
    scn[t] = d;
    __syncthreads();
    for (int off = 1; off < 256; off <<= 1) {
        int u = (t >= off) ? scn[t - off] : 0;
        __syncthreads();
        scn[t] += u;
        __syncthreads();
    }
    int o = sbase + scn[t] - d;       // exclusive global offset
    if (node < N) {
        offs[node] = o;
        ssrc[o] = node;               // self-loop first
        if (node == N - 1) offs[N] = o + d;
    }
    __syncthreads();
    cnt[t] = o + 1;                   // cursor past self-loop
    __syncthreads();
    for (int j = t; j < nb; j += 256) {
        unsigned v = ebuf[j];
        int dl = v & 255u;
        int pos = atomicAdd(&cnt[dl], 1);
        ssrc[pos] = (int)(v >> 8);
    }
}

// ---------------- K-agg: two-phase wave-cooperative segment softmax aggregate ----------------
__global__ __launch_bounds__(256) void k_aggregate(
    const int* __restrict__ offs, const int* __restrict__ ssrc,
    const unsigned short* __restrict__ xwb, const float* __restrict__ alsrc,
    const float* __restrict__ aldst, const float* __restrict__ bias,
    unsigned short* __restrict__ hout, int N)
{
    __shared__ float wls[4][32 * 8];   // 4 KB/wave
    int t = threadIdx.x;
    int wave = t >> 6, lane = t & 63;
    int n = blockIdx.x * 4 + wave;
    if (n >= N) return;
    int half = lane >> 5;          // which edge of the pair
    int cl = lane & 31;            // channel-pair index (channels 2cl, 2cl+1)
    int hp = cl >> 3;              // head (16 ch = 8 pairs per head)
    int s0 = offs[n], s1 = offs[n + 1];
    f32x4 adv = *(const f32x4*)(aldst + (size_t)n * 4);
    float* wl = wls[wave];
    int* wli = (int*)wl;
    const char* xb = (const char*)xwb;
    float ssum = 0.f, acc0 = 0.f, acc1 = 0.f;

    for (int c0 = s0; c0 < s1; c0 += 32) {
        int nb = s1 - c0; if (nb > 32) nb = 32;
        // ---- phase 1: lane = edge slot ----
        if (lane < nb) {
            int s = ssrc[c0 + lane];
            f32x4 al = *(const f32x4*)(alsrc + (size_t)s * 4);
            int o8 = lane * 8;
            int ob = s << 7;                           // s * 128 bytes
#pragma unroll
            for (int q = 0; q < 4; ++q) {
                float e = al[q] + adv[q];
                e = fmaxf(e, NEG_SLOPE * e);           // leaky_relu (slope<1)
                wl[o8 + 2 * q] = __expf(fminf(e, 60.f));
                wli[o8 + 2 * q + 1] = ob;
            }
        }
        // ---- phase 2: 2 edges per wave, 2 channels per lane; 8 gathers in flight ----
        int e = 0;
        for (; e + 16 <= nb; e += 16) {
#pragma unroll
            for (int u = 0; u < 8; ++u) {
                int idx = e + 2 * u + half;
                int bo = idx * 8 + hp * 2;
                float w = wl[bo];
                int   o = wli[bo + 1];
                unsigned pv = *(const unsigned*)(xb + o + cl * 4);
                union { unsigned u_; float f; } lo, hi;
                lo.u_ = pv << 16;
                hi.u_ = pv & 0xffff0000u;
                ssum += w;
                acc0 = fmaf(w, lo.f, acc0);
                acc1 = fmaf(w, hi.f, acc1);
            }
        }
        for (; e + 8 <= nb; e += 8) {
#pragma unroll
            for (int u = 0; u < 4; ++u) {
                int idx = e + 2 * u + half;
                int bo = idx * 8 + hp * 2;
                float w = wl[bo];
                int   o = wli[bo + 1];
                unsigned pv = *(const unsigned*)(xb + o + cl * 4);
                union { unsigned u_; float f; } lo, hi;
                lo.u_ = pv << 16;
                hi.u_ = pv & 0xffff0000u;
                ssum += w;
                acc0 = fmaf(w, lo.f, acc0);
                acc1 = fmaf(w, hi.f, acc1);
            }
        }
        for (; e < nb; e += 2) {
            int idx = e + half;
            if (idx < nb) {
                int bo = idx * 8 + hp * 2;
                float w = wl[bo];
                int   o = wli[bo + 1];
                unsigned pv = *(const unsigned*)(xb + o + cl * 4);
                union { unsigned u_; float f; } lo, hi;
                lo.u_ = pv << 16;
                hi.u_ = pv & 0xffff0000u;
                ssum += w;
                acc0 = fmaf(w, lo.f, acc0);
                acc1 = fmaf(w, hi.f, acc1);
            }
        }
    }

    // combine the two edge-halves
    ssum += __shfl_xor(ssum, 32, 64);
    acc0 += __shfl_xor(acc0, 32, 64);
    acc1 += __shfl_xor(acc1, 32, 64);
    float inv = 1.f / ssum;
    float2 bv = *(const float2*)(bias + 2 * cl);
    float h0 = fmaf(acc0, inv, bv.x);
    float h1 = fmaf(acc1, inv, bv.y);
    h0 = h0 > 0.f ? h0 : expm1f(h0);     // elu
    h1 = h1 > 0.f ? h1 : expm1f(h1);
    if (!half) {
        union { unsigned short s2[2]; unsigned u; } st;
        st.s2[0] = f2b(h0); st.s2[1] = f2b(h1);
        *(unsigned*)((char*)hout + ((size_t)n * 64 + cl * 2) * 2) = st.u;
    }
}

// ---------------- launch ----------------
extern "C" void kernel_launch(void* const* d_in, const int* in_sizes, int n_in,
                              void* d_out, int out_size, void* d_ws, size_t ws_size,
                              hipStream_t stream) {
    const float* x   = (const float*)d_in[0];
    const int*   ei  = (const int*)d_in[1];
    const float* W1  = (const float*)d_in[2];
    const float* a1s = (const float*)d_in[3];
    const float* a1d = (const float*)d_in[4];
    const float* b1  = (const float*)d_in[5];
    const float* W2  = (const float*)d_in[6];
    const float* a2s = (const float*)d_in[7];
    const float* a2d = (const float*)d_in[8];
    const float* b2  = (const float*)d_in[9];
    const float* Wp  = (const float*)d_in[10];
    const float* bp  = (const float*)d_in[11];
    float* out = (float*)d_out;

    const int N = in_sizes[0] / 128;
    const int E = in_sizes[1] / 2;
    const int Etot = E + N;
    const int NB = (N + 255) >> 8;    // buckets of 256 dst nodes (<=512)
    const int* esrc = ei;
    const int* edst = ei + E;

    // workspace layout (~75 MB)
    char* p = (char*)d_ws;
    auto alloc = [&](size_t bytes) {
        char* r = p;
        p += (bytes + 255) & ~(size_t)255;
        return (void*)r;
    };
    unsigned short* xw1b = (unsigned short*)alloc((size_t)N * 64 * 2);
    unsigned short* xw2b = (unsigned short*)alloc((size_t)N * 64 * 2);
    unsigned short* h1b  = (unsigned short*)alloc((size_t)N * 64 * 2);
    unsigned short* h2b  = (unsigned short*)alloc((size_t)N * 64 * 2);
    float* al1sv = (float*)alloc((size_t)N * 4 * 4);
    float* al1dv = (float*)alloc((size_t)N * 4 * 4);
    float* al2sv = (float*)alloc((size_t)N * 4 * 4);
    float* al2dv = (float*)alloc((size_t)N * 4 * 4);
    int*   offs  = (int*)alloc((size_t)(N + 1) * 4);
    int*   ssrc  = (int*)alloc((size_t)Etot * 4);
    int*   bcur  = (int*)alloc((size_t)NB * 4);
    unsigned* bbuf = (unsigned*)alloc((size_t)NB * BCAP * 4);
    (void)ws_size; (void)n_in; (void)out_size;

    dim3 blk(256);
    int gEchunk = (E + ECHUNK - 1) / ECHUNK;
    int gN4   = (N + 3) / 4;
    int gN64  = (N + 63) / 64;

    k_feat1<<<gN64, blk, 0, stream>>>(x, W1, a1s, a1d, xw1b, al1sv, al1dv, bcur, NB, N);
    k_bucket<<<gEchunk, blk, 0, stream>>>(esrc, edst, bcur, bbuf, E, NB);
    k_csr<<<NB, blk, 0, stream>>>(bcur, bbuf, offs, ssrc, N);
    k_aggregate<<<gN4, blk, 0, stream>>>(offs, ssrc, xw1b, al1sv, al1dv, b1, h1b, N);
    k_feat2<<<gN64, blk, 0, stream>>>(h1b, W2, a2s, a2d, xw2b, al2sv, al2dv, N);
    k_aggregate<<<gN4, blk, 0, stream>>>(offs, ssrc, xw2b, al2sv, al2dv, b2, h2b, N);
    k_proj<<<gN64, blk, 0, stream>>>(h2b, Wp, bp, out, N);
}